// Round 18
// baseline (9426.231 us; speedup 1.0000x reference)
//
#include <hip/hip_runtime.h>
#include <hip/hip_cooperative_groups.h>
#include <math.h>

namespace cg = cooperative_groups;

#define HWS 16  // log2(256*256)

typedef __attribute__((address_space(1))) const float gas_float;
typedef __attribute__((address_space(3))) float las_float;

// Async global->LDS 16B copy: per-lane global src (16B aligned), wave-uniform
// LDS base + lane*16.
__device__ __forceinline__ void gload_lds16(const float* src, float* ldsb) {
  __builtin_amdgcn_global_load_lds((gas_float*)src, (las_float*)ldsb, 16, 0, 0);
}

__device__ __forceinline__ float wsum(float v) {
#pragma unroll
  for (int o = 32; o > 0; o >>= 1) v += __shfl_down(v, o, 64);
  return v;
}

__device__ void fill_gauss(float* g) {
  if (threadIdx.x < 13) {
    double ssum = 0.0;
    for (int i = 0; i < 13; ++i) { double xi = (double)i - 6.0; ssum += exp(-(xi * xi) / 18.0); }
    double xk = (double)threadIdx.x - 6.0;
    g[threadIdx.x] = (float)(exp(-(xk * xk) / 18.0) / ssum);
  }
  __syncthreads();
}

// Direct 3x3 dilated conv, NCHW, 256x256, pad=DIL. Channel-concat: ic<ic0 -> in0 else in1.
// Tile 32x8 px, 1 px/thread, OCB oc/thread. 16B async staging (rows padded to 40 floats
// from x0-4, 4-aligned: every 16B run fully in-image or fully OOB -> zero page).
// Single buffer stage->drain->compute (r14 shape; pipelining attempts regressed:
// r6/r9/r11/r16 spill, r15 cache thrash). u-loop partially unrolled (x4) so weight
// s_loads pipeline across iterations.
// Optional BN-fusion: when bnpart != nullptr, the staged INPUT values are transformed
// in LDS as lrelu((x-m)*isd) with stats computed from bnpart in the prologue;
// OOB (zero-pad) elements stay 0 — matches reference pad-after-BN semantics.
template<int OCB, int ICB, int DIL>
__device__ void conv_stage(const float* __restrict__ in0, int ic0,
                           const float* __restrict__ in1,
                           const float* __restrict__ wt,   // [OC][IC][3][3]
                           float* __restrict__ out,
                           int nS, int IC, int OC, int act,
                           float* s, const float* zp,
                           const float2* __restrict__ bnpart, int bnC, float* sstl)
{
  constexpr int IWP = 40;                 // padded row width (floats)
  constexpr int IH = 8 + 2 * DIL;
  constexpr int CHP = IWP * IH;           // floats per channel
  constexpr int UPC = CHP / 4;            // 16B units per channel (10 per row)
  const int tid = threadIdx.x;
  const int tx = tid & 31, ty = tid >> 5;
  const int zc = OC / OCB;
  const int ic1n = IC - ic0;
  const int nTiles = 8 * 32 * nS * zc;

  // Prologue: fold BN stats (deterministic sequential 64-partial reduce, same
  // formula as the old bn_apply pass) into LDS. Visible after first barrier.
  if (bnpart) {
    for (int c = tid; c < bnC; c += 256) {
      float ssum = 0.f, qsum = 0.f;
      for (int p = 0; p < 64; ++p) { float2 pp = bnpart[c * 64 + p]; ssum += pp.x; qsum += pp.y; }
      const float inv = 1.0f / (4.0f * 65536.0f);
      float m = ssum * inv;
      float var = qsum * inv - m * m;
      sstl[2 * c] = m;
      sstl[2 * c + 1] = 1.0f / sqrtf(var + 1e-5f);
    }
  }

  for (int t = blockIdx.x; t < nTiles; t += gridDim.x) {
    const int bx = t & 7, r1 = t >> 3;
    const int by = r1 & 31, z = r1 >> 5;
    const int n = z / zc, ocBase = (z % zc) * OCB;
    const int x0 = bx * 32, y0 = by * 8;

    float acc[OCB];
#pragma unroll
    for (int j = 0; j < OCB; ++j) acc[j] = 0.f;

    for (int icg = 0; icg < IC; icg += ICB) {
      const int gcnt = (IC - icg < ICB) ? (IC - icg) : ICB;
      const int units = gcnt * UPC;
      const int nrounds = (units + 255) >> 8;
      for (int k = 0; k < nrounds; ++k) {
        if ((k << 8) + (tid & 192) < units) {   // wave-uniform guard
          const int j = (k << 8) + tid;
          const int jj = (j < units) ? j : 0;
          const int ch = jj / UPC, r2 = jj - ch * UPC;
          const int row = r2 / 10, cb = r2 - row * 10;
          const int ic = icg + ch;
          const float* inc = (ic < ic0)
              ? in0 + ((size_t)(n * ic0 + ic) << HWS)
              : in1 + ((size_t)(n * ic1n + (ic - ic0)) << HWS);
          const int gy = y0 - DIL + row;
          const int gx0 = x0 - 4 + (cb << 2);
          const bool ok = (j < units) && gy >= 0 && gy < 256 && gx0 >= 0 && gx0 < 256;
          const float* src = ok ? (inc + gy * 256 + gx0) : zp;
          gload_lds16(src, s + (k << 10) + ((tid & 192) << 2));
        }
      }
      __syncthreads();   // drains vmcnt -> staged data (and sstl) visible
      if (bnpart) {
        const int tot4 = gcnt * CHP;
        for (int i = tid; i < tot4; i += 256) {
          const int ch = i / CHP, r = i - ch * CHP;
          const int row = r / IWP, col = r - row * IWP;
          const int gy = y0 - DIL + row, gx = x0 - 4 + col;
          if (gy >= 0 && gy < 256 && gx >= 0 && gx < 256) {
            const int c = icg + ch;
            float v = (s[i] - sstl[2 * c]) * sstl[2 * c + 1];
            s[i] = v >= 0.f ? v : 0.1f * v;
          }
          // OOB elements are already 0 from the zero page: keep as pad.
        }
        __syncthreads();
      }
#pragma unroll 4
      for (int u = 0; u < gcnt; ++u) {
        float xi[9];
#pragma unroll
        for (int ky = 0; ky < 3; ++ky)
#pragma unroll
          for (int kx = 0; kx < 3; ++kx)
            xi[ky * 3 + kx] = s[u * CHP + (ty + ky * DIL) * IWP + tx + 4 + (kx - 1) * DIL];
        const float* wp = wt + ((size_t)ocBase * IC + (icg + u)) * 9;
#pragma unroll
        for (int j = 0; j < OCB; ++j) {
          const float* wj = wp + (size_t)j * IC * 9;
          float a = acc[j];
#pragma unroll
          for (int q = 0; q < 9; ++q) a = fmaf(xi[q], wj[q], a);
          acc[j] = a;
        }
      }
      __syncthreads();
    }
    const size_t pix = (size_t)(y0 + ty) * 256 + x0 + tx;
#pragma unroll
    for (int j = 0; j < OCB; ++j) {
      float v = acc[j];
      if (act) v = (v >= 0.f) ? v : 0.1f * v;
      out[((size_t)(n * OC + ocBase + j) << HWS) + pix] = v;
    }
  }
}

// Per-sample 49-offset local correlation (offsets -12+4*{0..6}, zero-pad OOB).
// 16B async staging, TWO channels per barrier-pair (896 units, 3584 LDS floats).
__device__ void lc_stage(const float* __restrict__ f1s, const float* __restrict__ f2,
                         float* __restrict__ lc, float* s, const float* zp)
{
  const int tid = threadIdx.x;
  const int tx = tid & 31, ty = tid >> 5;
  for (int t = blockIdx.x; t < 256; t += gridDim.x) {
    const int x0 = (t & 7) * 32, y0 = (t >> 3) * 8;
    const size_t pix = (size_t)(y0 + ty) * 256 + x0 + tx;
    float acc[49];
#pragma unroll
    for (int d = 0; d < 49; ++d) acc[d] = 0.f;
    for (int cp = 0; cp < 32; ++cp) {
      const int c0 = cp * 2;
      float f2v0 = f2[((size_t)c0 << HWS) + pix];         // in flight across staging
      float f2v1 = f2[((size_t)(c0 + 1) << HWS) + pix];
#pragma unroll
      for (int k = 0; k < 4; ++k) {
        if ((k << 8) + (tid & 192) < 896) {                // wave-uniform guard
          const int j = (k << 8) + tid;
          const int ch = j / 448, r = j - ch * 448;        // 448 16B-units per channel
          const int row = r / 14, cb = r - row * 14;
          const int gy = y0 - 12 + row;
          const int gx0 = x0 - 12 + (cb << 2);
          const bool ok = gy >= 0 && gy < 256 && gx0 >= 0 && gx0 < 256;
          const float* b1 = f1s + ((size_t)(c0 + ch) << HWS);
          const float* src = ok ? (b1 + gy * 256 + gx0) : zp;
          gload_lds16(src, s + (k << 10) + ((tid & 192) << 2));
        }
      }
      __syncthreads();
      for (int ch = 0; ch < 2; ++ch) {                     // ascending channel order
        const float f2v = ch ? f2v1 : f2v0;
        const float* sb = s + ch * 1792;
#pragma unroll
        for (int di = 0; di < 7; ++di)
#pragma unroll
          for (int dj = 0; dj < 7; ++dj) {
            float v = sb[(ty + di * 4) * 56 + tx + dj * 4];
            float df = f2v - v;
            acc[di * 7 + dj] = fmaf(df, df, acc[di * 7 + dj]);
          }
      }
      __syncthreads();
    }
#pragma unroll
    for (int d = 0; d < 49; ++d)
      lc[((size_t)d << HWS) + pix] = acc[d] * (1.f / 64.f);
  }
}

// Fused 13-tap separable blur: per 32x8 tile, stage 44x20 halo tile in LDS,
// vertical pass into LDS (44x8), horizontal pass to output.
__device__ void blur_fused_stage(const float* __restrict__ in, float* __restrict__ out,
                                 const float* g, int nPlanes, int mode, int fin, float* s)
{
  const int tid = threadIdx.x;
  const int tx = tid & 31, ty = tid >> 5;
  const int nT = nPlanes << 8;   // 256 tiles per plane
  for (int t = blockIdx.x; t < nT; t += gridDim.x) {
    const int tile = t & 255, pl = t >> 8;
    const int x0 = (tile & 7) * 32, y0 = (tile >> 3) * 8;
    const float* base = in + ((size_t)pl << HWS);
    for (int i = tid; i < 880; i += 256) {
      int rr = i / 44, cc = i - rr * 44;
      int gy = y0 - 6 + rr, gx = x0 - 6 + cc;
      float v = 0.f;
      if (mode) {
        gy = gy < 0 ? 0 : (gy > 255 ? 255 : gy);
        gx = gx < 0 ? 0 : (gx > 255 ? 255 : gx);
        v = base[gy * 256 + gx];
      } else if (gy >= 0 && gy < 256 && gx >= 0 && gx < 256) {
        v = base[gy * 256 + gx];
      }
      s[i] = v;
    }
    __syncthreads();
    for (int i = tid; i < 352; i += 256) {     // vertical: C[r 0..7][c 0..43]
      int r = i / 44, c = i - r * 44;
      float a = 0.f;
#pragma unroll
      for (int k = 0; k < 13; ++k) a = fmaf(g[k], s[(r + k) * 44 + c], a);
      s[880 + i] = a;
    }
    __syncthreads();
    {
      float a = 0.f;
#pragma unroll
      for (int k = 0; k < 13; ++k) a = fmaf(g[k], s[880 + ty * 44 + tx + k], a);
      if (fin) a = fminf(fmaxf(a, -300.f), 300.f) * (1.0f / 255.0f);
      out[((size_t)pl << HWS) + (size_t)(y0 + ty) * 256 + x0 + tx] = a;
    }
    __syncthreads();
  }
}

// BN partials: jobs = C*64, each reduces a 4096-element chunk of (N,H,W).
__device__ void bn_partial_stage(const float* __restrict__ x, float2* part, int C, float* sm)
{
  for (int job = blockIdx.x; job < C * 64; job += gridDim.x) {
    const int c = job >> 6, pb = job & 63;
    const int e0 = pb * 4096;
    float s = 0.f, q = 0.f;
    for (int i = threadIdx.x; i < 4096; i += 256) {
      int e = e0 + i;
      int nn = e >> HWS, p = e & 65535;
      float v = x[((size_t)(nn * C + c) << HWS) + p];
      s += v;
      q = fmaf(v, v, q);
    }
    s = wsum(s); q = wsum(q);
    __syncthreads();
    if ((threadIdx.x & 63) == 0) { sm[threadIdx.x >> 6] = s; sm[4 + (threadIdx.x >> 6)] = q; }
    __syncthreads();
    if (threadIdx.x == 0)
      part[job] = make_float2(sm[0] + sm[1] + sm[2] + sm[3], sm[4] + sm[5] + sm[6] + sm[7]);
  }
}

__global__ void __launch_bounds__(256, 8) disp_mega(
    const float* __restrict__ feat1, const float* __restrict__ feat2,
    const float* __restrict__ w_pre, const float* __restrict__ w_fc1,
    const float* __restrict__ w_fc2, const float* __restrict__ w_e0,
    const float* __restrict__ w_e1, const float* __restrict__ w_e2,
    const float* __restrict__ w_e3,
    float* __restrict__ outp,
    float* A, float* B, float* L, float* T, float* U,
    float2* part, float* zp)
{
  cg::grid_group grid = cg::this_grid();
  __shared__ float smem[4864];   // dil1 ICB12 staging cap; lc 2-ch uses 3584
  __shared__ float gtab[13];
  __shared__ float bnsm[8];
  __shared__ float sst[64];

  // e-chain buffers alias B (dead after per-sample loop: fc2 writes into A)
  float* e0b = B;                 // 4x32xHW
  float* e1b = B + 8388608;       // 4x16xHW
  float* e2b = B + 12582912;      // 4x8xHW
  float* e3b = B + 14680064;      // 4x2xHW

  // zero page for async-staging OOB runs (same-value write from every block;
  // fill_gauss's __syncthreads drains vmcnt before any staging read)
  if (threadIdx.x < 64) zp[threadIdx.x] = 0.f;
  fill_gauss(gtab);

  // S1: pre-conv (dil=1) on both inputs -> A (f1), B (f2)
  conv_stage<16, 12, 1>(feat1, 64, nullptr, w_pre, A, 4, 64, 64, 0, smem, zp, nullptr, 0, sst);
  conv_stage<16, 12, 1>(feat2, 64, nullptr, w_pre, B, 4, 64, 64, 0, smem, zp, nullptr, 0, sst);
  grid.sync();

  // Per-sample, 2 phases:
  //  P1: fc1(f1,f2)->T ; fused blur f1->U
  //  P2: lc(U,f2)->L ; fc2(T)->A[f1 slot]  (f1 dead after P1)
  for (int n = 0; n < 4; ++n) {
    const float* f1n = A + ((size_t)(n * 64) << HWS);
    float* f1nw = A + ((size_t)(n * 64) << HWS);
    const float* f2n = B + ((size_t)(n * 64) << HWS);
    float* lcn = L + ((size_t)(n * 49) << HWS);

    conv_stage<16, 12, 1>(f1n, 64, f2n, w_fc1, T, 1, 128, 128, 1, smem, zp, nullptr, 0, sst);
    blur_fused_stage(f1n, U, gtab, 64, 0, 0, smem);
    grid.sync();

    lc_stage(U, f2n, lcn, smem, zp);
    conv_stage<16, 12, 1>(T, 128, nullptr, w_fc2, f1nw, 1, 128, 64, 0, smem, zp, nullptr, 0, sst);
    grid.sync();
  }

  // e0: conv 113->32 dil1 (concat [A | L]); output raw (BN folded into e1 staging)
  conv_stage<16, 12, 1>(A, 64, L, w_e0, e0b, 4, 113, 32, 0, smem, zp, nullptr, 0, sst);
  grid.sync();
  bn_partial_stage(e0b, part, 32, bnsm);
  grid.sync();

  // e1: conv 32->16 dil2 on BN(e0) applied in staging; output raw
  conv_stage<16, 8, 2>(e0b, 32, nullptr, w_e1, e1b, 4, 32, 16, 0, smem, zp, part, 32, sst);
  grid.sync();
  bn_partial_stage(e1b, part, 16, bnsm);
  grid.sync();

  // e2: conv 16->8 dil4 on BN(e1) applied in staging; output raw
  conv_stage<8, 4, 4>(e1b, 16, nullptr, w_e2, e2b, 4, 16, 8, 0, smem, zp, part, 16, sst);
  grid.sync();
  bn_partial_stage(e2b, part, 8, bnsm);
  grid.sync();

  // e3: conv 8->2 dil1 on BN(e2) applied in staging (no BN/act on e3 output)
  conv_stage<2, 12, 1>(e2b, 8, nullptr, w_e3, e3b, 4, 8, 2, 0, smem, zp, part, 8, sst);
  grid.sync();

  // final fused blur (edge pad) + clip(+-300)/255 -> out
  blur_fused_stage(e3b, outp, gtab, 8, 1, 1, smem);
}

extern "C" void kernel_launch(void* const* d_in, const int* in_sizes, int n_in,
                              void* d_out, int out_size, void* d_ws, size_t ws_size,
                              hipStream_t stream)
{
  const float* feat1 = (const float*)d_in[0];
  const float* feat2 = (const float*)d_in[1];
  const float* w_pre = (const float*)d_in[2];
  const float* w_fc1 = (const float*)d_in[3];
  const float* w_fc2 = (const float*)d_in[4];
  const float* w_e0  = (const float*)d_in[5];
  const float* w_e1  = (const float*)d_in[6];
  const float* w_e2  = (const float*)d_in[7];
  const float* w_e3  = (const float*)d_in[8];
  float* outp = (float*)d_out;

  // Workspace layout (bytes); peak ~236 MB (validated rounds 2/3/5-17).
  const size_t offA = 0;             // 4x64xHW f1 (later fc2 outputs)
  const size_t offB = 67108864;      // 4x64xHW f2 (later e-chain)
  const size_t offL = 134217728;     // 4x49xHW lc
  const size_t offT = 185597952;     // 128xHW per-sample fc1
  const size_t offU = 219152384;     // 64xHW per-sample blurred f1
  const size_t offP = 235929856;     // bn partials (16KB)
  const size_t offZ = 235946496;     // zero page (256B, 16B-aligned)
  const size_t needed = 235946752;
  if (ws_size < needed) return;

  char* ws = (char*)d_ws;
  float* A = (float*)(ws + offA);
  float* B = (float*)(ws + offB);
  float* L = (float*)(ws + offL);
  float* T = (float*)(ws + offT);
  float* U = (float*)(ws + offU);
  float2* part = (float2*)(ws + offP);
  float* zp = (float*)(ws + offZ);

  int nb = 0;
  hipOccupancyMaxActiveBlocksPerMultiprocessor(&nb, (const void*)disp_mega, 256, 0);
  if (nb < 1) nb = 1;
  long long g = (long long)nb * 256;  // 256 CUs on MI355X
  if (g > 4096) g = 4096;

  void* args[] = { (void*)&feat1, (void*)&feat2, (void*)&w_pre, (void*)&w_fc1,
                   (void*)&w_fc2, (void*)&w_e0, (void*)&w_e1, (void*)&w_e2,
                   (void*)&w_e3, (void*)&outp, (void*)&A, (void*)&B, (void*)&L,
                   (void*)&T, (void*)&U, (void*)&part, (void*)&zp };
  hipLaunchCooperativeKernel((const void*)disp_mega, dim3((unsigned)g), dim3(256),
                             args, 0, stream);
}

// Round 19
// 6573.474 us; speedup vs baseline: 1.4340x; 1.4340x over previous
//
#include <hip/hip_runtime.h>
#include <hip/hip_cooperative_groups.h>
#include <math.h>

namespace cg = cooperative_groups;

#define HWS 16  // log2(256*256)

typedef __attribute__((address_space(1))) const float gas_float;
typedef __attribute__((address_space(3))) float las_float;

// Async global->LDS 16B copy: per-lane global src (16B aligned), wave-uniform
// LDS base + lane*16.
__device__ __forceinline__ void gload_lds16(const float* src, float* ldsb) {
  __builtin_amdgcn_global_load_lds((gas_float*)src, (las_float*)ldsb, 16, 0, 0);
}

__device__ __forceinline__ float wsum(float v) {
#pragma unroll
  for (int o = 32; o > 0; o >>= 1) v += __shfl_down(v, o, 64);
  return v;
}

__device__ void fill_gauss(float* g) {
  if (threadIdx.x < 13) {
    double ssum = 0.0;
    for (int i = 0; i < 13; ++i) { double xi = (double)i - 6.0; ssum += exp(-(xi * xi) / 18.0); }
    double xk = (double)threadIdx.x - 6.0;
    g[threadIdx.x] = (float)(exp(-(xk * xk) / 18.0) / ssum);
  }
  __syncthreads();
}

// Direct 3x3 dilated conv, NCHW, 256x256, pad=DIL. Channel-concat: ic<ic0 -> in0 else in1.
// Tile 32x8 px, 1 px/thread, OCB oc/thread. 16B async staging (rows padded to 40 floats
// from x0-4, 4-aligned: every 16B run fully in-image or fully OOB -> zero page).
// Single buffer stage->drain->compute; plain runtime u-loop (r17 shape — unroll-4
// regressed via rematerialization at the 32-VGPR clamp, r18).
// Optional BN-fusion: when bnpart != nullptr, the staged INPUT values are transformed
// in LDS as lrelu((x-m)*isd) with stats computed from bnpart in the prologue;
// OOB (zero-pad) elements stay 0 — matches reference pad-after-BN semantics.
template<int OCB, int ICB, int DIL>
__device__ void conv_stage(const float* __restrict__ in0, int ic0,
                           const float* __restrict__ in1,
                           const float* __restrict__ wt,   // [OC][IC][3][3]
                           float* __restrict__ out,
                           int nS, int IC, int OC, int act,
                           float* s, const float* zp,
                           const float2* __restrict__ bnpart, int bnC, float* sstl)
{
  constexpr int IWP = 40;                 // padded row width (floats)
  constexpr int IH = 8 + 2 * DIL;
  constexpr int CHP = IWP * IH;           // floats per channel
  constexpr int UPC = CHP / 4;            // 16B units per channel (10 per row)
  const int tid = threadIdx.x;
  const int tx = tid & 31, ty = tid >> 5;
  const int zc = OC / OCB;
  const int ic1n = IC - ic0;
  const int nTiles = 8 * 32 * nS * zc;

  // Prologue: fold BN stats (deterministic sequential 64-partial reduce, same
  // formula as the old bn_apply pass) into LDS. Visible after first barrier.
  if (bnpart) {
    for (int c = tid; c < bnC; c += 256) {
      float ssum = 0.f, qsum = 0.f;
      for (int p = 0; p < 64; ++p) { float2 pp = bnpart[c * 64 + p]; ssum += pp.x; qsum += pp.y; }
      const float inv = 1.0f / (4.0f * 65536.0f);
      float m = ssum * inv;
      float var = qsum * inv - m * m;
      sstl[2 * c] = m;
      sstl[2 * c + 1] = 1.0f / sqrtf(var + 1e-5f);
    }
  }

  for (int t = blockIdx.x; t < nTiles; t += gridDim.x) {
    const int bx = t & 7, r1 = t >> 3;
    const int by = r1 & 31, z = r1 >> 5;
    const int n = z / zc, ocBase = (z % zc) * OCB;
    const int x0 = bx * 32, y0 = by * 8;

    float acc[OCB];
#pragma unroll
    for (int j = 0; j < OCB; ++j) acc[j] = 0.f;

    for (int icg = 0; icg < IC; icg += ICB) {
      const int gcnt = (IC - icg < ICB) ? (IC - icg) : ICB;
      const int units = gcnt * UPC;
      const int nrounds = (units + 255) >> 8;
      for (int k = 0; k < nrounds; ++k) {
        if ((k << 8) + (tid & 192) < units) {   // wave-uniform guard
          const int j = (k << 8) + tid;
          const int jj = (j < units) ? j : 0;
          const int ch = jj / UPC, r2 = jj - ch * UPC;
          const int row = r2 / 10, cb = r2 - row * 10;
          const int ic = icg + ch;
          const float* inc = (ic < ic0)
              ? in0 + ((size_t)(n * ic0 + ic) << HWS)
              : in1 + ((size_t)(n * ic1n + (ic - ic0)) << HWS);
          const int gy = y0 - DIL + row;
          const int gx0 = x0 - 4 + (cb << 2);
          const bool ok = (j < units) && gy >= 0 && gy < 256 && gx0 >= 0 && gx0 < 256;
          const float* src = ok ? (inc + gy * 256 + gx0) : zp;
          gload_lds16(src, s + (k << 10) + ((tid & 192) << 2));
        }
      }
      __syncthreads();   // drains vmcnt -> staged data (and sstl) visible
      if (bnpart) {
        const int tot4 = gcnt * CHP;
        for (int i = tid; i < tot4; i += 256) {
          const int ch = i / CHP, r = i - ch * CHP;
          const int row = r / IWP, col = r - row * IWP;
          const int gy = y0 - DIL + row, gx = x0 - 4 + col;
          if (gy >= 0 && gy < 256 && gx >= 0 && gx < 256) {
            const int c = icg + ch;
            float v = (s[i] - sstl[2 * c]) * sstl[2 * c + 1];
            s[i] = v >= 0.f ? v : 0.1f * v;
          }
          // OOB elements are already 0 from the zero page: keep as pad.
        }
        __syncthreads();
      }
      for (int u = 0; u < gcnt; ++u) {
        float xi[9];
#pragma unroll
        for (int ky = 0; ky < 3; ++ky)
#pragma unroll
          for (int kx = 0; kx < 3; ++kx)
            xi[ky * 3 + kx] = s[u * CHP + (ty + ky * DIL) * IWP + tx + 4 + (kx - 1) * DIL];
        const float* wp = wt + ((size_t)ocBase * IC + (icg + u)) * 9;
#pragma unroll
        for (int j = 0; j < OCB; ++j) {
          const float* wj = wp + (size_t)j * IC * 9;
          float a = acc[j];
#pragma unroll
          for (int q = 0; q < 9; ++q) a = fmaf(xi[q], wj[q], a);
          acc[j] = a;
        }
      }
      __syncthreads();
    }
    const size_t pix = (size_t)(y0 + ty) * 256 + x0 + tx;
#pragma unroll
    for (int j = 0; j < OCB; ++j) {
      float v = acc[j];
      if (act) v = (v >= 0.f) ? v : 0.1f * v;
      out[((size_t)(n * OC + ocBase + j) << HWS) + pix] = v;
    }
  }
}

// Per-sample 49-offset local correlation (offsets -12+4*{0..6}, zero-pad OOB).
// 16B async staging, TWO channels per barrier-pair (896 units, 3584 LDS floats).
__device__ void lc_stage(const float* __restrict__ f1s, const float* __restrict__ f2,
                         float* __restrict__ lc, float* s, const float* zp)
{
  const int tid = threadIdx.x;
  const int tx = tid & 31, ty = tid >> 5;
  for (int t = blockIdx.x; t < 256; t += gridDim.x) {
    const int x0 = (t & 7) * 32, y0 = (t >> 3) * 8;
    const size_t pix = (size_t)(y0 + ty) * 256 + x0 + tx;
    float acc[49];
#pragma unroll
    for (int d = 0; d < 49; ++d) acc[d] = 0.f;
    for (int cp = 0; cp < 32; ++cp) {
      const int c0 = cp * 2;
      float f2v0 = f2[((size_t)c0 << HWS) + pix];         // in flight across staging
      float f2v1 = f2[((size_t)(c0 + 1) << HWS) + pix];
#pragma unroll
      for (int k = 0; k < 4; ++k) {
        if ((k << 8) + (tid & 192) < 896) {                // wave-uniform guard
          const int j = (k << 8) + tid;
          const int ch = j / 448, r = j - ch * 448;        // 448 16B-units per channel
          const int row = r / 14, cb = r - row * 14;
          const int gy = y0 - 12 + row;
          const int gx0 = x0 - 12 + (cb << 2);
          const bool ok = gy >= 0 && gy < 256 && gx0 >= 0 && gx0 < 256;
          const float* b1 = f1s + ((size_t)(c0 + ch) << HWS);
          const float* src = ok ? (b1 + gy * 256 + gx0) : zp;
          gload_lds16(src, s + (k << 10) + ((tid & 192) << 2));
        }
      }
      __syncthreads();
      for (int ch = 0; ch < 2; ++ch) {                     // ascending channel order
        const float f2v = ch ? f2v1 : f2v0;
        const float* sb = s + ch * 1792;
#pragma unroll
        for (int di = 0; di < 7; ++di)
#pragma unroll
          for (int dj = 0; dj < 7; ++dj) {
            float v = sb[(ty + di * 4) * 56 + tx + dj * 4];
            float df = f2v - v;
            acc[di * 7 + dj] = fmaf(df, df, acc[di * 7 + dj]);
          }
      }
      __syncthreads();
    }
#pragma unroll
    for (int d = 0; d < 49; ++d)
      lc[((size_t)d << HWS) + pix] = acc[d] * (1.f / 64.f);
  }
}

// Fused 13-tap separable blur: per 32x8 tile, stage 44x20 halo tile in LDS,
// vertical pass into LDS (44x8), horizontal pass to output.
__device__ void blur_fused_stage(const float* __restrict__ in, float* __restrict__ out,
                                 const float* g, int nPlanes, int mode, int fin, float* s)
{
  const int tid = threadIdx.x;
  const int tx = tid & 31, ty = tid >> 5;
  const int nT = nPlanes << 8;   // 256 tiles per plane
  for (int t = blockIdx.x; t < nT; t += gridDim.x) {
    const int tile = t & 255, pl = t >> 8;
    const int x0 = (tile & 7) * 32, y0 = (tile >> 3) * 8;
    const float* base = in + ((size_t)pl << HWS);
    for (int i = tid; i < 880; i += 256) {
      int rr = i / 44, cc = i - rr * 44;
      int gy = y0 - 6 + rr, gx = x0 - 6 + cc;
      float v = 0.f;
      if (mode) {
        gy = gy < 0 ? 0 : (gy > 255 ? 255 : gy);
        gx = gx < 0 ? 0 : (gx > 255 ? 255 : gx);
        v = base[gy * 256 + gx];
      } else if (gy >= 0 && gy < 256 && gx >= 0 && gx < 256) {
        v = base[gy * 256 + gx];
      }
      s[i] = v;
    }
    __syncthreads();
    for (int i = tid; i < 352; i += 256) {     // vertical: C[r 0..7][c 0..43]
      int r = i / 44, c = i - r * 44;
      float a = 0.f;
#pragma unroll
      for (int k = 0; k < 13; ++k) a = fmaf(g[k], s[(r + k) * 44 + c], a);
      s[880 + i] = a;
    }
    __syncthreads();
    {
      float a = 0.f;
#pragma unroll
      for (int k = 0; k < 13; ++k) a = fmaf(g[k], s[880 + ty * 44 + tx + k], a);
      if (fin) a = fminf(fmaxf(a, -300.f), 300.f) * (1.0f / 255.0f);
      out[((size_t)pl << HWS) + (size_t)(y0 + ty) * 256 + x0 + tx] = a;
    }
    __syncthreads();
  }
}

// BN partials: jobs = C*64, each reduces a 4096-element chunk of (N,H,W).
__device__ void bn_partial_stage(const float* __restrict__ x, float2* part, int C, float* sm)
{
  for (int job = blockIdx.x; job < C * 64; job += gridDim.x) {
    const int c = job >> 6, pb = job & 63;
    const int e0 = pb * 4096;
    float s = 0.f, q = 0.f;
    for (int i = threadIdx.x; i < 4096; i += 256) {
      int e = e0 + i;
      int nn = e >> HWS, p = e & 65535;
      float v = x[((size_t)(nn * C + c) << HWS) + p];
      s += v;
      q = fmaf(v, v, q);
    }
    s = wsum(s); q = wsum(q);
    __syncthreads();
    if ((threadIdx.x & 63) == 0) { sm[threadIdx.x >> 6] = s; sm[4 + (threadIdx.x >> 6)] = q; }
    __syncthreads();
    if (threadIdx.x == 0)
      part[job] = make_float2(sm[0] + sm[1] + sm[2] + sm[3], sm[4] + sm[5] + sm[6] + sm[7]);
  }
}

__global__ void __launch_bounds__(256, 8) disp_mega(
    const float* __restrict__ feat1, const float* __restrict__ feat2,
    const float* __restrict__ w_pre, const float* __restrict__ w_fc1,
    const float* __restrict__ w_fc2, const float* __restrict__ w_e0,
    const float* __restrict__ w_e1, const float* __restrict__ w_e2,
    const float* __restrict__ w_e3,
    float* __restrict__ outp,
    float* A, float* B, float* L, float* T, float* U,
    float2* part, float* zp)
{
  cg::grid_group grid = cg::this_grid();
  __shared__ float smem[4864];   // dil1 ICB12 staging cap; lc 2-ch uses 3584
  __shared__ float gtab[13];
  __shared__ float bnsm[8];
  __shared__ float sst[64];

  // e-chain buffers alias B (dead after per-sample loop: fc2 writes into A)
  float* e0b = B;                 // 4x32xHW
  float* e1b = B + 8388608;       // 4x16xHW
  float* e2b = B + 12582912;      // 4x8xHW
  float* e3b = B + 14680064;      // 4x2xHW

  // zero page for async-staging OOB runs (same-value write from every block;
  // fill_gauss's __syncthreads drains vmcnt before any staging read)
  if (threadIdx.x < 64) zp[threadIdx.x] = 0.f;
  fill_gauss(gtab);

  // S1: pre-conv (dil=1) on both inputs -> A (f1), B (f2)
  conv_stage<16, 12, 1>(feat1, 64, nullptr, w_pre, A, 4, 64, 64, 0, smem, zp, nullptr, 0, sst);
  conv_stage<16, 12, 1>(feat2, 64, nullptr, w_pre, B, 4, 64, 64, 0, smem, zp, nullptr, 0, sst);
  grid.sync();

  // Per-sample, 2 phases:
  //  P1: fc1(f1,f2)->T ; fused blur f1->U
  //  P2: lc(U,f2)->L ; fc2(T)->A[f1 slot]  (f1 dead after P1)
  for (int n = 0; n < 4; ++n) {
    const float* f1n = A + ((size_t)(n * 64) << HWS);
    float* f1nw = A + ((size_t)(n * 64) << HWS);
    const float* f2n = B + ((size_t)(n * 64) << HWS);
    float* lcn = L + ((size_t)(n * 49) << HWS);

    conv_stage<16, 12, 1>(f1n, 64, f2n, w_fc1, T, 1, 128, 128, 1, smem, zp, nullptr, 0, sst);
    blur_fused_stage(f1n, U, gtab, 64, 0, 0, smem);
    grid.sync();

    lc_stage(U, f2n, lcn, smem, zp);
    conv_stage<16, 12, 1>(T, 128, nullptr, w_fc2, f1nw, 1, 128, 64, 0, smem, zp, nullptr, 0, sst);
    grid.sync();
  }

  // e0: conv 113->32 dil1 (concat [A | L]); output raw (BN folded into e1 staging)
  conv_stage<16, 12, 1>(A, 64, L, w_e0, e0b, 4, 113, 32, 0, smem, zp, nullptr, 0, sst);
  grid.sync();
  bn_partial_stage(e0b, part, 32, bnsm);
  grid.sync();

  // e1: conv 32->16 dil2 on BN(e0) applied in staging; output raw
  conv_stage<16, 8, 2>(e0b, 32, nullptr, w_e1, e1b, 4, 32, 16, 0, smem, zp, part, 32, sst);
  grid.sync();
  bn_partial_stage(e1b, part, 16, bnsm);
  grid.sync();

  // e2: conv 16->8 dil4 on BN(e1) applied in staging; output raw
  conv_stage<8, 4, 4>(e1b, 16, nullptr, w_e2, e2b, 4, 16, 8, 0, smem, zp, part, 16, sst);
  grid.sync();
  bn_partial_stage(e2b, part, 8, bnsm);
  grid.sync();

  // e3: conv 8->2 dil1 on BN(e2) applied in staging (no BN/act on e3 output)
  conv_stage<2, 12, 1>(e2b, 8, nullptr, w_e3, e3b, 4, 8, 2, 0, smem, zp, part, 8, sst);
  grid.sync();

  // final fused blur (edge pad) + clip(+-300)/255 -> out
  blur_fused_stage(e3b, outp, gtab, 8, 1, 1, smem);
}

extern "C" void kernel_launch(void* const* d_in, const int* in_sizes, int n_in,
                              void* d_out, int out_size, void* d_ws, size_t ws_size,
                              hipStream_t stream)
{
  const float* feat1 = (const float*)d_in[0];
  const float* feat2 = (const float*)d_in[1];
  const float* w_pre = (const float*)d_in[2];
  const float* w_fc1 = (const float*)d_in[3];
  const float* w_fc2 = (const float*)d_in[4];
  const float* w_e0  = (const float*)d_in[5];
  const float* w_e1  = (const float*)d_in[6];
  const float* w_e2  = (const float*)d_in[7];
  const float* w_e3  = (const float*)d_in[8];
  float* outp = (float*)d_out;

  // Workspace layout (bytes); peak ~236 MB (validated rounds 2/3/5-18).
  const size_t offA = 0;             // 4x64xHW f1 (later fc2 outputs)
  const size_t offB = 67108864;      // 4x64xHW f2 (later e-chain)
  const size_t offL = 134217728;     // 4x49xHW lc
  const size_t offT = 185597952;     // 128xHW per-sample fc1
  const size_t offU = 219152384;     // 64xHW per-sample blurred f1
  const size_t offP = 235929856;     // bn partials (16KB)
  const size_t offZ = 235946496;     // zero page (256B, 16B-aligned)
  const size_t needed = 235946752;
  if (ws_size < needed) return;

  char* ws = (char*)d_ws;
  float* A = (float*)(ws + offA);
  float* B = (float*)(ws + offB);
  float* L = (float*)(ws + offL);
  float* T = (float*)(ws + offT);
  float* U = (float*)(ws + offU);
  float2* part = (float2*)(ws + offP);
  float* zp = (float*)(ws + offZ);

  int nb = 0;
  hipOccupancyMaxActiveBlocksPerMultiprocessor(&nb, (const void*)disp_mega, 256, 0);
  if (nb < 1) nb = 1;
  long long g = (long long)nb * 256;  // 256 CUs on MI355X
  if (g > 4096) g = 4096;

  void* args[] = { (void*)&feat1, (void*)&feat2, (void*)&w_pre, (void*)&w_fc1,
                   (void*)&w_fc2, (void*)&w_e0, (void*)&w_e1, (void*)&w_e2,
                   (void*)&w_e3, (void*)&outp, (void*)&A, (void*)&B, (void*)&L,
                   (void*)&T, (void*)&U, (void*)&part, (void*)&zp };
  hipLaunchCooperativeKernel((const void*)disp_mega, dim3((unsigned)g), dim3(256),
                             args, 0, stream);
}